// Round 1
// baseline (858.476 us; speedup 1.0000x reference)
//
#include <hip/hip_runtime.h>
#include <hip/hip_bf16.h>

#define TT   4096
#define HH   1024
#define FF   3584
#define EE   8
#define N13  7168   // 2*FF
#define TKP  8192   // TT * top_k

#define BM 128
#define BN 128
#define BK 64
#define LDK 72      // padded LDS inner dim (elements); 144B row stride, 16B aligned

typedef unsigned short u16;
typedef __attribute__((ext_vector_type(8))) short short8;
typedef __attribute__((ext_vector_type(4))) float floatx4;

__device__ __forceinline__ u16 f2b(float f) {
  union { float f; unsigned u; } v; v.f = f;
  unsigned r = v.u + 0x7FFFu + ((v.u >> 16) & 1u);   // RNE
  return (u16)(r >> 16);
}
__device__ __forceinline__ float b2f(u16 u) {
  union { unsigned u; float f; } v; v.u = ((unsigned)u) << 16; return v.f;
}
__device__ __forceinline__ float blo(unsigned u) {
  union { unsigned u; float f; } v; v.u = u << 16; return v.f;
}
__device__ __forceinline__ float bhi(unsigned u) {
  union { unsigned u; float f; } v; v.u = u & 0xFFFF0000u; return v.f;
}

// ---------------- conversions ----------------
__global__ __launch_bounds__(256) void cvt_x(const float4* __restrict__ in, ushort4* __restrict__ outp) {
  int i = blockIdx.x * 256 + threadIdx.x;
  float4 v = in[i];
  ushort4 o; o.x = f2b(v.x); o.y = f2b(v.y); o.z = f2b(v.z); o.w = f2b(v.w);
  outp[i] = o;
}

// w13b[e][n][h]: n<FF -> w1[e][n][h], n>=FF -> w3[e][n-FF][h]
__global__ __launch_bounds__(256) void cvt_w13(const float* __restrict__ w1, const float* __restrict__ w3,
                                               ushort4* __restrict__ w13b) {
  int i = blockIdx.x * 256 + threadIdx.x;      // float4 index
  const int perE = N13 * (HH / 4);
  int e = i / perE;
  int rem = i - e * perE;
  int n = rem / (HH / 4);
  int h4 = rem - n * (HH / 4);
  const float4* src = (n < FF)
      ? ((const float4*)(w1 + (size_t)(e * FF + n) * HH)) + h4
      : ((const float4*)(w3 + (size_t)(e * FF + (n - FF)) * HH)) + h4;
  float4 v = *src;
  ushort4 o; o.x = f2b(v.x); o.y = f2b(v.y); o.z = f2b(v.z); o.w = f2b(v.w);
  w13b[i] = o;
}

__global__ __launch_bounds__(256) void cvt_w2(const float4* __restrict__ in, ushort4* __restrict__ outp) {
  int i = blockIdx.x * 256 + threadIdx.x;
  float4 v = in[i];
  ushort4 o; o.x = f2b(v.x); o.y = f2b(v.y); o.z = f2b(v.z); o.w = f2b(v.w);
  outp[i] = o;
}

// ---------------- router ----------------
__global__ __launch_bounds__(256) void router(const float* __restrict__ x, const float* __restrict__ gw,
                                              int* __restrict__ cnt, int* __restrict__ tok_list,
                                              float* __restrict__ wt_list) {
  int lane = threadIdx.x & 63;
  int wv = threadIdx.x >> 6;
  int t = blockIdx.x * 4 + wv;
  const float* xp = x + (size_t)t * HH;
  float acc[EE];
#pragma unroll
  for (int e = 0; e < EE; e++) acc[e] = 0.f;
  for (int h = lane; h < HH; h += 64) {
    float xv = xp[h];
#pragma unroll
    for (int e = 0; e < EE; e++) acc[e] += xv * gw[e * HH + h];
  }
#pragma unroll
  for (int e = 0; e < EE; e++) {
#pragma unroll
    for (int off = 32; off > 0; off >>= 1) acc[e] += __shfl_xor(acc[e], off, 64);
  }
  if (lane == 0) {
    int i1 = 0;
#pragma unroll
    for (int e = 1; e < EE; e++) if (acc[e] > acc[i1]) i1 = e;
    int i2 = -1;
#pragma unroll
    for (int e = 0; e < EE; e++) {
      if (e == i1) continue;
      if (i2 < 0 || acc[e] > acc[i2]) i2 = e;
    }
    // normalized top-2 softmax weights: w1 = p1/(p1+p2) = 1/(1+exp(l2-l1))
    float wA = 1.f / (1.f + __expf(acc[i2] - acc[i1]));
    float wB = 1.f - wA;
    int p1 = atomicAdd(cnt + i1, 1);
    tok_list[i1 * TT + p1] = t; wt_list[i1 * TT + p1] = wA;
    int p2 = atomicAdd(cnt + i2, 1);
    tok_list[i2 * TT + p2] = t; wt_list[i2 * TT + p2] = wB;
  }
}

__global__ void mk_offsets(const int* __restrict__ cnt, int* __restrict__ offs) {
  if (threadIdx.x == 0) {
    int s = 0;
    for (int e = 0; e < EE; e++) { offs[e] = s; s += cnt[e]; }
  }
}

__global__ __launch_bounds__(256) void pairmap(const int* __restrict__ cnt, const int* __restrict__ offs,
                                               const int* __restrict__ tok_list, const float* __restrict__ wt_list,
                                               int* __restrict__ tokp, float* __restrict__ wtp) {
  int i = blockIdx.x * 256 + threadIdx.x;   // e*TT + s
  int e = i >> 12;
  int s = i & (TT - 1);
  if (s < cnt[e]) {
    int p = offs[e] + s;
    tokp[p] = tok_list[i];
    wtp[p] = wt_list[i];
  }
}

// ---------------- GEMM A: h13[pair][n] = x[tok] . w13[e][n][:] ----------------
__global__ __launch_bounds__(256) void gemm_a(const u16* __restrict__ xb, const u16* __restrict__ w13b,
                                              const int* __restrict__ cnt, const int* __restrict__ offs,
                                              const int* __restrict__ tok_list, u16* __restrict__ h13) {
  const int ntile = blockIdx.x;            // 0..55
  const int e = blockIdx.y >> 5;
  const int rt = blockIdx.y & 31;
  const int cn = cnt[e];
  if (rt * BM >= cn) return;

  __shared__ u16 As[BM][LDK];
  __shared__ u16 Bs[BN][LDK];
  __shared__ int toks[BM];

  const int tid = threadIdx.x;
  if (tid < BM) {
    int r = rt * BM + tid;
    if (r >= cn) r = cn - 1;
    toks[tid] = tok_list[e * TT + r];
  }
  __syncthreads();

  const int r0 = tid >> 3;               // rows r0, r0+32, r0+64, r0+96
  const int c0 = (tid & 7) * 8;          // 8 bf16 per 16B chunk
  const u16* aptr[4];
  const u16* bptr[4];
#pragma unroll
  for (int i = 0; i < 4; i++) {
    int r = r0 + i * 32;
    aptr[i] = xb + (size_t)toks[r] * HH + c0;
    bptr[i] = w13b + ((size_t)e * N13 + (size_t)ntile * BN + r) * HH + c0;
  }

  const int lane = tid & 63;
  const int wv = tid >> 6;
  const int wr = (wv >> 1) * 64;
  const int wc = (wv & 1) * 64;
  const int fr = lane & 15;
  const int fk = (lane >> 4) * 8;

  floatx4 acc[4][4];
#pragma unroll
  for (int mi = 0; mi < 4; mi++)
#pragma unroll
    for (int ni = 0; ni < 4; ni++)
#pragma unroll
      for (int q = 0; q < 4; q++) acc[mi][ni][q] = 0.f;

  for (int k0 = 0; k0 < HH; k0 += BK) {
#pragma unroll
    for (int i = 0; i < 4; i++) {
      uint4 av = *(const uint4*)(aptr[i]); aptr[i] += BK;
      uint4 bv = *(const uint4*)(bptr[i]); bptr[i] += BK;
      *(uint4*)&As[r0 + i * 32][c0] = av;
      *(uint4*)&Bs[r0 + i * 32][c0] = bv;
    }
    __syncthreads();
#pragma unroll
    for (int ks = 0; ks < 2; ks++) {
      short8 af[4], bfr[4];
#pragma unroll
      for (int mi = 0; mi < 4; mi++) af[mi] = *(const short8*)&As[wr + mi * 16 + fr][ks * 32 + fk];
#pragma unroll
      for (int ni = 0; ni < 4; ni++) bfr[ni] = *(const short8*)&Bs[wc + ni * 16 + fr][ks * 32 + fk];
#pragma unroll
      for (int mi = 0; mi < 4; mi++)
#pragma unroll
        for (int ni = 0; ni < 4; ni++)
          acc[mi][ni] = __builtin_amdgcn_mfma_f32_16x16x32_bf16(af[mi], bfr[ni], acc[mi][ni], 0, 0, 0);
    }
    __syncthreads();
  }

  const int gofs = offs[e];
#pragma unroll
  for (int mi = 0; mi < 4; mi++) {
#pragma unroll
    for (int i = 0; i < 4; i++) {
      int r = wr + mi * 16 + (lane >> 4) * 4 + i;
      int gr = rt * BM + r;
      if (gr < cn) {
        u16* dst = h13 + (size_t)(gofs + gr) * N13 + (size_t)ntile * BN + wc + (lane & 15);
#pragma unroll
        for (int ni = 0; ni < 4; ni++) dst[ni * 16] = f2b(acc[mi][ni][i]);
      }
    }
  }
}

// ---------------- SwiGLU: g = silu(h1)*h3*wt ----------------
__global__ __launch_bounds__(256) void silu_k(const u16* __restrict__ h13, const float* __restrict__ wtp,
                                              u16* __restrict__ g) {
  int i = blockIdx.x * 256 + threadIdx.x;   // over TKP * FF/8
  int p = i / (FF / 8);
  int f8 = i - p * (FF / 8);
  const u16* row = h13 + (size_t)p * N13 + f8 * 8;
  uint4 va = *(const uint4*)(row);
  uint4 vb = *(const uint4*)(row + FF);
  float w = wtp[p];
  unsigned ua[4] = {va.x, va.y, va.z, va.w};
  unsigned ub[4] = {vb.x, vb.y, vb.z, vb.w};
  unsigned uo[4];
#pragma unroll
  for (int j = 0; j < 4; j++) {
    float a0 = blo(ua[j]), a1 = bhi(ua[j]);
    float b0 = blo(ub[j]), b1 = bhi(ub[j]);
    float s0 = a0 / (1.f + __expf(-a0));
    float s1 = a1 / (1.f + __expf(-a1));
    u16 o0 = f2b(s0 * b0 * w);
    u16 o1 = f2b(s1 * b1 * w);
    uo[j] = (unsigned)o0 | ((unsigned)o1 << 16);
  }
  uint4 vo; vo.x = uo[0]; vo.y = uo[1]; vo.z = uo[2]; vo.w = uo[3];
  *(uint4*)(g + (size_t)p * FF + f8 * 8) = vo;
}

// ---------------- GEMM B: out[tok] += g[pair] . w2[e][h][:] ----------------
__global__ __launch_bounds__(256) void gemm_b(const u16* __restrict__ g, const u16* __restrict__ w2b,
                                              const int* __restrict__ cnt, const int* __restrict__ offs,
                                              const int* __restrict__ tokp, float* __restrict__ out) {
  const int ntile = blockIdx.x;            // 0..7
  const int e = blockIdx.y >> 5;
  const int rt = blockIdx.y & 31;
  const int cn = cnt[e];
  if (rt * BM >= cn) return;
  const int gofs = offs[e];

  __shared__ u16 As[BM][LDK];
  __shared__ u16 Bs[BN][LDK];
  __shared__ int toks[BM];

  const int tid = threadIdx.x;
  if (tid < BM) {
    int r = rt * BM + tid;
    if (r >= cn) r = cn - 1;
    toks[tid] = tokp[gofs + r];
  }
  __syncthreads();

  const int r0 = tid >> 3;
  const int c0 = (tid & 7) * 8;
  const u16* aptr[4];
  const u16* bptr[4];
#pragma unroll
  for (int i = 0; i < 4; i++) {
    int r = r0 + i * 32;
    int gr = rt * BM + r;
    if (gr >= cn) gr = cn - 1;
    aptr[i] = g + (size_t)(gofs + gr) * FF + c0;
    bptr[i] = w2b + ((size_t)e * HH + (size_t)ntile * BN + r) * FF + c0;
  }

  const int lane = tid & 63;
  const int wv = tid >> 6;
  const int wr = (wv >> 1) * 64;
  const int wc = (wv & 1) * 64;
  const int fr = lane & 15;
  const int fk = (lane >> 4) * 8;

  floatx4 acc[4][4];
#pragma unroll
  for (int mi = 0; mi < 4; mi++)
#pragma unroll
    for (int ni = 0; ni < 4; ni++)
#pragma unroll
      for (int q = 0; q < 4; q++) acc[mi][ni][q] = 0.f;

  for (int k0 = 0; k0 < FF; k0 += BK) {
#pragma unroll
    for (int i = 0; i < 4; i++) {
      uint4 av = *(const uint4*)(aptr[i]); aptr[i] += BK;
      uint4 bv = *(const uint4*)(bptr[i]); bptr[i] += BK;
      *(uint4*)&As[r0 + i * 32][c0] = av;
      *(uint4*)&Bs[r0 + i * 32][c0] = bv;
    }
    __syncthreads();
#pragma unroll
    for (int ks = 0; ks < 2; ks++) {
      short8 af[4], bfr[4];
#pragma unroll
      for (int mi = 0; mi < 4; mi++) af[mi] = *(const short8*)&As[wr + mi * 16 + fr][ks * 32 + fk];
#pragma unroll
      for (int ni = 0; ni < 4; ni++) bfr[ni] = *(const short8*)&Bs[wc + ni * 16 + fr][ks * 32 + fk];
#pragma unroll
      for (int mi = 0; mi < 4; mi++)
#pragma unroll
        for (int ni = 0; ni < 4; ni++)
          acc[mi][ni] = __builtin_amdgcn_mfma_f32_16x16x32_bf16(af[mi], bfr[ni], acc[mi][ni], 0, 0, 0);
    }
    __syncthreads();
  }

#pragma unroll
  for (int mi = 0; mi < 4; mi++) {
#pragma unroll
    for (int i = 0; i < 4; i++) {
      int r = wr + mi * 16 + (lane >> 4) * 4 + i;
      int gr = rt * BM + r;
      if (gr < cn) {
        int tk = toks[r];
        float* dst = out + (size_t)tk * HH + (size_t)ntile * BN + wc + (lane & 15);
#pragma unroll
        for (int ni = 0; ni < 4; ni++) atomicAdd(dst + ni * 16, acc[mi][ni][i]);
      }
    }
  }
}

extern "C" void kernel_launch(void* const* d_in, const int* in_sizes, int n_in,
                              void* d_out, int out_size, void* d_ws, size_t ws_size,
                              hipStream_t stream) {
  const float* x  = (const float*)d_in[0];
  const float* gw = (const float*)d_in[1];
  const float* w1 = (const float*)d_in[2];
  const float* w2 = (const float*)d_in[3];
  const float* w3 = (const float*)d_in[4];
  float* out = (float*)d_out;

  char* ws = (char*)d_ws;
  u16* xb    = (u16*)ws;  ws += (size_t)TT * HH * 2;          // 8 MB
  u16* w13b  = (u16*)ws;  ws += (size_t)EE * N13 * HH * 2;    // 117 MB
  u16* w2b   = (u16*)ws;  ws += (size_t)EE * HH * FF * 2;     // 59 MB
  u16* h13   = (u16*)ws;  ws += (size_t)TKP * N13 * 2;        // 117 MB
  u16* gbuf  = (u16*)ws;  ws += (size_t)TKP * FF * 2;         // 59 MB
  int* cnt   = (int*)ws;  ws += 256;
  int* offs  = (int*)ws;  ws += 256;
  int* tok_list = (int*)ws;   ws += (size_t)EE * TT * 4;
  float* wt_list = (float*)ws; ws += (size_t)EE * TT * 4;
  int* tokp  = (int*)ws;  ws += (size_t)TKP * 4;
  float* wtp = (float*)ws; ws += (size_t)TKP * 4;

  hipMemsetAsync(cnt, 0, 256, stream);
  hipMemsetAsync(out, 0, (size_t)TT * HH * 4, stream);

  cvt_x<<<(TT * HH / 4) / 256, 256, 0, stream>>>((const float4*)x, (ushort4*)xb);
  cvt_w13<<<(EE * N13 * (HH / 4)) / 256, 256, 0, stream>>>(w1, w3, (ushort4*)w13b);
  cvt_w2<<<(EE * HH * (FF / 4)) / 256, 256, 0, stream>>>((const float4*)w2, (ushort4*)w2b);

  router<<<TT / 4, 256, 0, stream>>>(x, gw, cnt, tok_list, wt_list);
  mk_offsets<<<1, 64, 0, stream>>>(cnt, offs);
  pairmap<<<(EE * TT) / 256, 256, 0, stream>>>(cnt, offs, tok_list, wt_list, tokp, wtp);

  gemm_a<<<dim3(N13 / BN, EE * (TT / BM)), 256, 0, stream>>>(xb, w13b, cnt, offs, tok_list, h13);
  silu_k<<<(TKP * (FF / 8)) / 256, 256, 0, stream>>>(h13, wtp, gbuf);
  gemm_b<<<dim3(HH / BN, EE * (TT / BM)), 256, 0, stream>>>(gbuf, w2b, cnt, offs, tokp, out);
}

// Round 2
// 738.240 us; speedup vs baseline: 1.1629x; 1.1629x over previous
//
#include <hip/hip_runtime.h>
#include <hip/hip_bf16.h>

#define TT   4096
#define HH   1024
#define FF   3584
#define EE   8
#define N13  7168   // 2*FF (interleaved w1/w3 at 16-col granularity)
#define TKP  8192   // TT * top_k

#define BM 128
#define BN 128
#define BK 64

typedef unsigned short u16;
typedef __attribute__((ext_vector_type(8))) short short8;
typedef __attribute__((ext_vector_type(4))) float floatx4;

__device__ __forceinline__ u16 f2b(float f) {
  union { float f; unsigned u; } v; v.f = f;
  unsigned r = v.u + 0x7FFFu + ((v.u >> 16) & 1u);   // RNE
  return (u16)(r >> 16);
}

// async global->LDS, 16 bytes per lane. LDS dst semantics: wave-uniform base
// + lane*16; our per-lane dst pointer equals exactly that.
__device__ __forceinline__ void gld_lds16(const u16* g, u16* l) {
  __builtin_amdgcn_global_load_lds((const __attribute__((address_space(1))) unsigned int*)g,
                                   (__attribute__((address_space(3))) unsigned int*)l,
                                   16, 0, 0);
}

// ---------------- conversions ----------------
__global__ __launch_bounds__(256) void cvt_x(const float4* __restrict__ in, ushort4* __restrict__ outp) {
  int i = blockIdx.x * 256 + threadIdx.x;
  float4 v = in[i];
  ushort4 o; o.x = f2b(v.x); o.y = f2b(v.y); o.z = f2b(v.z); o.w = f2b(v.w);
  outp[i] = o;
}

// w13i[e][n][h]: n -> f=(n>>5)*16+(n&15), sel=(n>>4)&1 ; sel=0 -> w1[e][f], sel=1 -> w3[e][f]
__global__ __launch_bounds__(256) void cvt_w13(const float* __restrict__ w1, const float* __restrict__ w3,
                                               ushort4* __restrict__ w13i) {
  int i = blockIdx.x * 256 + threadIdx.x;      // float4 index in dest
  const int perE = N13 * (HH / 4);
  int e = i / perE;
  int rem = i - e * perE;
  int n = rem / (HH / 4);
  int h4 = rem - n * (HH / 4);
  int f = ((n >> 5) << 4) + (n & 15);
  int sel = (n >> 4) & 1;
  const float* base = sel ? w3 : w1;
  const float4* src = ((const float4*)(base + (size_t)(e * FF + f) * HH)) + h4;
  float4 v = *src;
  ushort4 o; o.x = f2b(v.x); o.y = f2b(v.y); o.z = f2b(v.z); o.w = f2b(v.w);
  w13i[i] = o;
}

__global__ __launch_bounds__(256) void cvt_w2(const float4* __restrict__ in, ushort4* __restrict__ outp) {
  int i = blockIdx.x * 256 + threadIdx.x;
  float4 v = in[i];
  ushort4 o; o.x = f2b(v.x); o.y = f2b(v.y); o.z = f2b(v.z); o.w = f2b(v.w);
  outp[i] = o;
}

// ---------------- router ----------------
__global__ __launch_bounds__(256) void router(const float* __restrict__ x, const float* __restrict__ gw,
                                              int* __restrict__ cnt, int* __restrict__ tok_list,
                                              float* __restrict__ wt_list) {
  int lane = threadIdx.x & 63;
  int wv = threadIdx.x >> 6;
  int t = blockIdx.x * 4 + wv;
  const float* xp = x + (size_t)t * HH;
  float acc[EE];
#pragma unroll
  for (int e = 0; e < EE; e++) acc[e] = 0.f;
  for (int h = lane; h < HH; h += 64) {
    float xv = xp[h];
#pragma unroll
    for (int e = 0; e < EE; e++) acc[e] += xv * gw[e * HH + h];
  }
#pragma unroll
  for (int e = 0; e < EE; e++) {
#pragma unroll
    for (int off = 32; off > 0; off >>= 1) acc[e] += __shfl_xor(acc[e], off, 64);
  }
  if (lane == 0) {
    int i1 = 0;
#pragma unroll
    for (int e = 1; e < EE; e++) if (acc[e] > acc[i1]) i1 = e;
    int i2 = -1;
#pragma unroll
    for (int e = 0; e < EE; e++) {
      if (e == i1) continue;
      if (i2 < 0 || acc[e] > acc[i2]) i2 = e;
    }
    float wA = 1.f / (1.f + __expf(acc[i2] - acc[i1]));
    float wB = 1.f - wA;
    int p1 = atomicAdd(cnt + i1, 1);
    tok_list[i1 * TT + p1] = t; wt_list[i1 * TT + p1] = wA;
    int p2 = atomicAdd(cnt + i2, 1);
    tok_list[i2 * TT + p2] = t; wt_list[i2 * TT + p2] = wB;
  }
}

__global__ void mk_offsets(const int* __restrict__ cnt, int* __restrict__ offs) {
  if (threadIdx.x == 0) {
    int s = 0;
    for (int e = 0; e < EE; e++) { offs[e] = s; s += cnt[e]; }
  }
}

__global__ __launch_bounds__(256) void pairmap(const int* __restrict__ cnt, const int* __restrict__ offs,
                                               const int* __restrict__ tok_list,
                                               int* __restrict__ tokp) {
  int i = blockIdx.x * 256 + threadIdx.x;   // e*TT + s
  int e = i >> 12;
  int s = i & (TT - 1);
  if (s < cnt[e]) {
    tokp[offs[e] + s] = tok_list[i];
  }
}

// ---------------- GEMM A + fused SwiGLU ----------------
// g[pair][f] = silu(x.w1[f]) * (x.w3[f]) * route_wt
__global__ __launch_bounds__(256) void gemm_a(const u16* __restrict__ xb, const u16* __restrict__ w13i,
                                              const int* __restrict__ cnt, const int* __restrict__ offs,
                                              const int* __restrict__ tok_list, const float* __restrict__ wt_list,
                                              u16* __restrict__ gbuf) {
  const int ntile = blockIdx.x;            // 0..55 (64 f-values each)
  const int e = blockIdx.y >> 5;
  const int rt = blockIdx.y & 31;
  const int cn = cnt[e];
  if (rt * BM >= cn) return;

  __shared__ u16 As[BM * BK];   // row-major 128x64, XOR-swizzled cols (8-elt granules)
  __shared__ u16 Bs[BN * BK];
  __shared__ int toks[BM];
  __shared__ float wts[BM];

  const int tid = threadIdx.x;
  if (tid < BM) {
    int r = rt * BM + tid;
    if (r >= cn) r = cn - 1;
    toks[tid] = tok_list[e * TT + r];
    wts[tid] = wt_list[e * TT + r];
  }
  __syncthreads();

  // staging: pass i covers rows (tid>>3)+i*32 ; source col granule is swizzled
  const u16* aptr[4];
  const u16* bptr[4];
  u16* alds[4];
  u16* blds[4];
#pragma unroll
  for (int i = 0; i < 4; i++) {
    int row = (tid >> 3) + i * 32;
    int c8 = (tid & 7) ^ (row & 7);         // logical granule for this phys slot
    aptr[i] = xb + (size_t)toks[row] * HH + c8 * 8;
    bptr[i] = w13i + ((size_t)e * N13 + (size_t)ntile * BN + row) * HH + c8 * 8;
    alds[i] = As + row * BK + (tid & 7) * 8;  // == wave-uniform base + lane*16B
    blds[i] = Bs + row * BK + (tid & 7) * 8;
  }

  const int lane = tid & 63;
  const int wv = tid >> 6;
  const int wr = (wv >> 1) * 64;
  const int wc = (wv & 1) * 64;
  const int fr = lane & 15;
  const int fk8 = lane >> 4;                // k-granule index (0..3)

  floatx4 acc[4][4];
#pragma unroll
  for (int mi = 0; mi < 4; mi++)
#pragma unroll
    for (int ni = 0; ni < 4; ni++)
#pragma unroll
      for (int q = 0; q < 4; q++) acc[mi][ni][q] = 0.f;

  for (int k0 = 0; k0 < HH; k0 += BK) {
#pragma unroll
    for (int i = 0; i < 4; i++) {
      gld_lds16(aptr[i], alds[i]); aptr[i] += BK;
      gld_lds16(bptr[i], blds[i]); bptr[i] += BK;
    }
    __syncthreads();
#pragma unroll
    for (int ks = 0; ks < 2; ks++) {
      int c8 = (ks * 4 + fk8) ^ (fr & 7);   // de-swizzle
      short8 af[4], bfr[4];
#pragma unroll
      for (int mi = 0; mi < 4; mi++) af[mi] = *(const short8*)&As[(wr + mi * 16 + fr) * BK + c8 * 8];
#pragma unroll
      for (int ni = 0; ni < 4; ni++) bfr[ni] = *(const short8*)&Bs[(wc + ni * 16 + fr) * BK + c8 * 8];
#pragma unroll
      for (int mi = 0; mi < 4; mi++)
#pragma unroll
        for (int ni = 0; ni < 4; ni++)
          acc[mi][ni] = __builtin_amdgcn_mfma_f32_16x16x32_bf16(af[mi], bfr[ni], acc[mi][ni], 0, 0, 0);
    }
    __syncthreads();
  }

  // fused SwiGLU epilogue: cols (ni, ni^1) are the (w1,w3) pair for
  // f = wc/2 + (ni>>1)*16 + (lane&15)
  const int gofs = offs[e];
  const int cl = lane & 15;
#pragma unroll
  for (int mi = 0; mi < 4; mi++) {
#pragma unroll
    for (int q = 0; q < 4; q++) {
      int r = wr + mi * 16 + (lane >> 4) * 4 + q;
      int gr = rt * BM + r;
      if (gr < cn) {
        float w = wts[r];
        u16* dst = gbuf + (size_t)(gofs + gr) * FF + (size_t)ntile * 64 + wc / 2 + cl;
#pragma unroll
        for (int pg = 0; pg < 2; pg++) {
          float h1 = acc[mi][2 * pg][q];
          float h3 = acc[mi][2 * pg + 1][q];
          float s = h1 / (1.f + __expf(-h1));
          dst[pg * 16] = f2b(s * h3 * w);
        }
      }
    }
  }
}

// ---------------- GEMM B: out[tok] += g[pair] . w2[e][h][:] ----------------
__global__ __launch_bounds__(256) void gemm_b(const u16* __restrict__ g, const u16* __restrict__ w2b,
                                              const int* __restrict__ cnt, const int* __restrict__ offs,
                                              const int* __restrict__ tokp, float* __restrict__ out) {
  const int ntile = blockIdx.x;            // 0..7
  const int e = blockIdx.y >> 5;
  const int rt = blockIdx.y & 31;
  const int cn = cnt[e];
  if (rt * BM >= cn) return;
  const int gofs = offs[e];

  __shared__ u16 As[BM * BK];
  __shared__ u16 Bs[BN * BK];
  __shared__ int toks[BM];

  const int tid = threadIdx.x;
  if (tid < BM) {
    int r = rt * BM + tid;
    if (r >= cn) r = cn - 1;
    toks[tid] = tokp[gofs + r];
  }
  __syncthreads();

  const u16* aptr[4];
  const u16* bptr[4];
  u16* alds[4];
  u16* blds[4];
#pragma unroll
  for (int i = 0; i < 4; i++) {
    int row = (tid >> 3) + i * 32;
    int gr = rt * BM + row;
    if (gr >= cn) gr = cn - 1;
    int c8 = (tid & 7) ^ (row & 7);
    aptr[i] = g + (size_t)(gofs + gr) * FF + c8 * 8;
    bptr[i] = w2b + ((size_t)e * HH + (size_t)ntile * BN + row) * FF + c8 * 8;
    alds[i] = As + row * BK + (tid & 7) * 8;
    blds[i] = Bs + row * BK + (tid & 7) * 8;
  }

  const int lane = tid & 63;
  const int wv = tid >> 6;
  const int wr = (wv >> 1) * 64;
  const int wc = (wv & 1) * 64;
  const int fr = lane & 15;
  const int fk8 = lane >> 4;

  floatx4 acc[4][4];
#pragma unroll
  for (int mi = 0; mi < 4; mi++)
#pragma unroll
    for (int ni = 0; ni < 4; ni++)
#pragma unroll
      for (int q = 0; q < 4; q++) acc[mi][ni][q] = 0.f;

  for (int k0 = 0; k0 < FF; k0 += BK) {
#pragma unroll
    for (int i = 0; i < 4; i++) {
      gld_lds16(aptr[i], alds[i]); aptr[i] += BK;
      gld_lds16(bptr[i], blds[i]); bptr[i] += BK;
    }
    __syncthreads();
#pragma unroll
    for (int ks = 0; ks < 2; ks++) {
      int c8 = (ks * 4 + fk8) ^ (fr & 7);
      short8 af[4], bfr[4];
#pragma unroll
      for (int mi = 0; mi < 4; mi++) af[mi] = *(const short8*)&As[(wr + mi * 16 + fr) * BK + c8 * 8];
#pragma unroll
      for (int ni = 0; ni < 4; ni++) bfr[ni] = *(const short8*)&Bs[(wc + ni * 16 + fr) * BK + c8 * 8];
#pragma unroll
      for (int mi = 0; mi < 4; mi++)
#pragma unroll
        for (int ni = 0; ni < 4; ni++)
          acc[mi][ni] = __builtin_amdgcn_mfma_f32_16x16x32_bf16(af[mi], bfr[ni], acc[mi][ni], 0, 0, 0);
    }
    __syncthreads();
  }

#pragma unroll
  for (int mi = 0; mi < 4; mi++) {
#pragma unroll
    for (int q = 0; q < 4; q++) {
      int r = wr + mi * 16 + (lane >> 4) * 4 + q;
      int gr = rt * BM + r;
      if (gr < cn) {
        int tk = toks[r];
        float* dst = out + (size_t)tk * HH + (size_t)ntile * BN + wc + (lane & 15);
#pragma unroll
        for (int ni = 0; ni < 4; ni++) atomicAdd(dst + ni * 16, acc[mi][ni][q]);
      }
    }
  }
}

extern "C" void kernel_launch(void* const* d_in, const int* in_sizes, int n_in,
                              void* d_out, int out_size, void* d_ws, size_t ws_size,
                              hipStream_t stream) {
  const float* x  = (const float*)d_in[0];
  const float* gw = (const float*)d_in[1];
  const float* w1 = (const float*)d_in[2];
  const float* w2 = (const float*)d_in[3];
  const float* w3 = (const float*)d_in[4];
  float* out = (float*)d_out;

  char* ws = (char*)d_ws;
  u16* xb    = (u16*)ws;  ws += (size_t)TT * HH * 2;          // 8 MB
  u16* w13i  = (u16*)ws;  ws += (size_t)EE * N13 * HH * 2;    // 117 MB
  u16* w2b   = (u16*)ws;  ws += (size_t)EE * HH * FF * 2;     // 59 MB
  u16* gbuf  = (u16*)ws;  ws += (size_t)TKP * FF * 2;         // 59 MB
  int* cnt   = (int*)ws;  ws += 256;
  int* offs  = (int*)ws;  ws += 256;
  int* tok_list = (int*)ws;   ws += (size_t)EE * TT * 4;
  float* wt_list = (float*)ws; ws += (size_t)EE * TT * 4;
  int* tokp  = (int*)ws;  ws += (size_t)TKP * 4;

  hipMemsetAsync(cnt, 0, 256, stream);
  hipMemsetAsync(out, 0, (size_t)TT * HH * 4, stream);

  cvt_x<<<(TT * HH / 4) / 256, 256, 0, stream>>>((const float4*)x, (ushort4*)xb);
  cvt_w13<<<(EE * N13 * (HH / 4)) / 256, 256, 0, stream>>>(w1, w3, (ushort4*)w13i);
  cvt_w2<<<(EE * HH * (FF / 4)) / 256, 256, 0, stream>>>((const float4*)w2, (ushort4*)w2b);

  router<<<TT / 4, 256, 0, stream>>>(x, gw, cnt, tok_list, wt_list);
  mk_offsets<<<1, 64, 0, stream>>>(cnt, offs);
  pairmap<<<(EE * TT) / 256, 256, 0, stream>>>(cnt, offs, tok_list, tokp);

  gemm_a<<<dim3(N13 / BN, EE * (TT / BM)), 256, 0, stream>>>(xb, w13i, cnt, offs, tok_list, wt_list, gbuf);
  gemm_b<<<dim3(HH / BN, EE * (TT / BM)), 256, 0, stream>>>(gbuf, w2b, cnt, offs, tokp, out);
}